// Round 5
// baseline (346.397 us; speedup 1.0000x reference)
//
#include <hip/hip_runtime.h>
#include <hip/hip_bf16.h>

// Char-LSTM via MFMA, round 5.
// Round-4 failure root cause: raw inline-asm v_exp_f32/v_rcp_f32 — TRANS-op
// result hazards are invisible to the compiler inside INLINEASM, so dependent
// VALU ops consumed stale registers. Same folded-exp2 math now goes through
// __builtin_amdgcn_exp2f/__builtin_amdgcn_rcpf (compiler-scheduled, hazard-safe).
// - G^T[256][16] = Whh'(bf16)[256][64] x H^T(bf16)[64][16] per step, C-init = xtab'.
// - Gate rows PRE-SCALED (i,f,o by -log2e; g by +2log2e): sigmoid = rcp(1+exp2(d)),
//   tanh = 1-2*rcp(1+exp2(d)).
// - 1 sorted group of 16 words per wave, 4096 waves, 4 waves/SIMD (VGPR<=128).
//   Length-class mixing across a block's 4 waves for balance.
// - maxl via true wave-max over the group's 16 lanes (robust to sort order).

#define VOCAB 100
#define E     32
#define NW    65536
#define MAXL  16
#define NGRP  4096   // NW/16

typedef __bf16 bf16x8 __attribute__((ext_vector_type(8)));
typedef float  f32x4  __attribute__((ext_vector_type(4)));
typedef unsigned short ushort_t;
typedef unsigned int uint_t;

#define LOG2E    1.4426950408889634f
#define TWOLOG2E 2.8853900817779268f

__device__ __forceinline__ ushort_t f2bf(float x) {
    union { __hip_bfloat16 b; ushort_t u; } cv;
    cv.b = __float2bfloat16(x);
    return cv.u;
}
__device__ __forceinline__ float exp2_hw(float x) { return __builtin_amdgcn_exp2f(x); }
__device__ __forceinline__ float rcp_hw(float x)  { return __builtin_amdgcn_rcpf(x); }

// ---- fused prep: xtab [100][256] f32 (scaled), Wb [256][64] bf16 (scaled), hist ----
__global__ void prep_fused(const float* __restrict__ emb, const float* __restrict__ Wih,
                           const float* __restrict__ Whh, const float* __restrict__ bih,
                           const float* __restrict__ bhh, const int* __restrict__ lengths,
                           float* __restrict__ xtab, ushort_t* __restrict__ Wb,
                           int* __restrict__ bh) {
    int bid = blockIdx.x;
    if (bid < VOCAB) {                         // xtab row: g = q*64+u (torch row order)
        int ch = bid, g = threadIdx.x, q = g >> 6;
        float scl = (q == 2) ? TWOLOG2E : -LOG2E;
        float acc = bih[g] + bhh[g];
        const float* er = emb + ch * E;
        const float* wr = Wih + g * E;
        #pragma unroll
        for (int e = 0; e < E; ++e) acc = fmaf(er[e], wr[e], acc);
        xtab[ch * 256 + g] = acc * scl;
    } else if (bid < VOCAB + 64) {             // Wb = bf16(scaled Whh), [256][64]
        int i = (bid - VOCAB) * 256 + threadIdx.x;
        int q = i >> 12;                       // gate quarter of row i>>6
        float scl = (q == 2) ? TWOLOG2E : -LOG2E;
        Wb[i] = f2bf(Whh[i] * scl);
    } else {                                   // per-block length histogram
        int blk = bid - (VOCAB + 64);          // 0..255
        __shared__ int h[16];
        if (threadIdx.x < 16) h[threadIdx.x] = 0;
        __syncthreads();
        atomicAdd(&h[lengths[blk * 256 + threadIdx.x] - 1], 1);
        __syncthreads();
        if (threadIdx.x < 16) bh[blk * 16 + threadIdx.x] = h[threadIdx.x];
    }
}

// parallel exclusive prefix: bases[blk][b] = gb[b] + sum_{blk'<blk} bh[blk'][b]
__global__ void k_bases(const int* __restrict__ bh, int* __restrict__ bases) {
    __shared__ int chunk[16][16], chunkpre[16][16], tot[16], gb[16];
    int t = threadIdx.x, b = t & 15, cs = t >> 4;
    int s = 0;
    #pragma unroll
    for (int i = 0; i < 16; ++i) s += bh[(cs * 16 + i) * 16 + b];
    chunk[cs][b] = s;
    __syncthreads();
    if (t < 16) {                              // thread b scans chunks of bucket b
        int a = 0;
        for (int c2 = 0; c2 < 16; ++c2) { chunkpre[c2][b] = a; a += chunk[c2][b]; }
        tot[b] = a;
    }
    __syncthreads();
    if (t == 0) { int a = 0; for (int i = 0; i < 16; ++i) { gb[i] = a; a += tot[i]; } }
    __syncthreads();
    int base = gb[b] + chunkpre[cs][b];
    for (int i = 0; i < 16; ++i) {
        bases[(cs * 16 + i) * 16 + b] = base;
        base += bh[(cs * 16 + i) * 16 + b];
    }
}

__global__ void k_scatter(const int* __restrict__ lengths, const int* __restrict__ bases,
                          int* __restrict__ perm) {
    __shared__ int h[16];
    if (threadIdx.x < 16) h[threadIdx.x] = 0;
    __syncthreads();
    int w = blockIdx.x * 256 + threadIdx.x;
    int b = lengths[w] - 1;
    int r = atomicAdd(&h[b], 1);
    perm[bases[blockIdx.x * 16 + b] + r] = w;
}

// ---- main ----
__global__ __launch_bounds__(256, 4) void lstm_main(
    const ushort_t* __restrict__ Wb, const float* __restrict__ xtab,
    const int* __restrict__ chars, const int* __restrict__ lengths,
    const int* __restrict__ perm, float* __restrict__ out)
{
    __shared__ __align__(16) char Hlds_all[4][2048];
    char* Hbase = Hlds_all[threadIdx.x >> 6];

    const int lane = threadIdx.x & 63;
    const int w  = lane & 15;                  // word slot (MFMA N-col)
    const int lq = lane >> 4;                  // lane quad
    // length-class mixing: block's 4 waves get classes {c, c+4, c+8, c+12}
    const int widx = threadIdx.x >> 6;
    const int cls  = ((blockIdx.x & 3) << 2) | widx;
    const int grp  = (cls << 8) | (blockIdx.x >> 2);     // 0..4095

    // A-fragments (weights). Compiler may reload from L1 per step - acceptable.
    bf16x8 a[16][2];
    #pragma unroll
    for (int m = 0; m < 16; ++m)
        #pragma unroll
        for (int kh = 0; kh < 2; ++kh)
            a[m][kh] = *reinterpret_cast<const bf16x8*>(Wb + ((m * 16 + w) * 64 + kh * 32 + lq * 8));

    // Swizzled per-wave LDS bounce offsets for H (write/read same involution).
    const int sw = (w & 7) << 4;
    const int base_w = w * 128;
    int wr_off[4], rd_off[2];
    #pragma unroll
    for (int b = 0; b < 4; ++b) wr_off[b] = base_w + ((b * 32 + lq * 8) ^ sw);
    #pragma unroll
    for (int kh = 0; kh < 2; ++kh) rd_off[kh] = base_w + ((kh * 64 + lq * 16) ^ sw);

    const int wid = perm[grp * 16 + w];
    const int len = lengths[wid];
    // robust group-max length (independent of sort order): max over the 16 slots
    int ml = len;
    ml = max(ml, __shfl_xor(ml, 1));
    ml = max(ml, __shfl_xor(ml, 2));
    ml = max(ml, __shfl_xor(ml, 4));
    ml = max(ml, __shfl_xor(ml, 8));
    const int maxl = __builtin_amdgcn_readfirstlane(ml);
    const int* chp = chars + wid * MAXL;

    float hreg[4][4], creg[4][4];
    #pragma unroll
    for (int b = 0; b < 4; ++b)
        #pragma unroll
        for (int r = 0; r < 4; ++r) { hreg[b][r] = 0.f; creg[b][r] = 0.f; }

    int ch = chp[0];
    const float* xrow = xtab + ch * 256;
    f32x4 xtb[2][4];
    #pragma unroll
    for (int q = 0; q < 4; ++q)
        xtb[0][q] = *reinterpret_cast<const f32x4*>(xrow + (q * 4 + 0) * 16 + lq * 4);

    #pragma unroll 1
    for (int t = 0; t < maxl; ++t) {
        const int tn = (t + 1 < maxl) ? t + 1 : t;
        const int ch_nxt = chp[tn];
        const float* xrow_n = xtab + ch_nxt * 256;

        bf16x8 B0, B1;
        if (t > 0) {
            asm volatile("s_waitcnt lgkmcnt(0)" ::: "memory");   // prev-step H writes
            B0 = *reinterpret_cast<const bf16x8*>(Hbase + rd_off[0]);
            B1 = *reinterpret_cast<const bf16x8*>(Hbase + rd_off[1]);
        }
        const bool act = (t < len);

        #pragma unroll
        for (int b = 0; b < 4; ++b) {
            if (b < 3) {
                #pragma unroll
                for (int q = 0; q < 4; ++q)
                    xtb[(b + 1) & 1][q] = *reinterpret_cast<const f32x4*>(xrow + (q * 4 + b + 1) * 16 + lq * 4);
            } else {
                #pragma unroll
                for (int q = 0; q < 4; ++q)
                    xtb[0][q] = *reinterpret_cast<const f32x4*>(xrow_n + q * 64 + lq * 4);
            }
            f32x4 d[4];
            #pragma unroll
            for (int q = 0; q < 4; ++q) d[q] = xtb[b & 1][q];
            if (t > 0) {
                #pragma unroll
                for (int q = 0; q < 4; ++q) {
                    d[q] = __builtin_amdgcn_mfma_f32_16x16x32_bf16(a[q * 4 + b][0], B0, d[q], 0, 0, 0);
                    d[q] = __builtin_amdgcn_mfma_f32_16x16x32_bf16(a[q * 4 + b][1], B1, d[q], 0, 0, 0);
                }
            }
            // activations in exp2-folded space: d0=i', d1=f', d2=g', d3=o'
            #pragma unroll
            for (int r = 0; r < 4; ++r) {
                float ig = rcp_hw(1.f + exp2_hw(d[0][r]));
                float fg = rcp_hw(1.f + exp2_hw(d[1][r]));
                float gg = fmaf(-2.f, rcp_hw(1.f + exp2_hw(d[2][r])), 1.f);
                float og = rcp_hw(1.f + exp2_hw(d[3][r]));
                float cn = fmaf(fg, creg[b][r], ig * gg);
                float tc = fmaf(-2.f, rcp_hw(1.f + exp2_hw(cn * TWOLOG2E)), 1.f);
                float hn = og * tc;
                creg[b][r] = act ? cn : creg[b][r];
                hreg[b][r] = act ? hn : hreg[b][r];
            }
            uint_t lo = (uint_t)f2bf(hreg[b][0]) | ((uint_t)f2bf(hreg[b][1]) << 16);
            uint_t hi = (uint_t)f2bf(hreg[b][2]) | ((uint_t)f2bf(hreg[b][3]) << 16);
            *reinterpret_cast<uint2*>(Hbase + wr_off[b]) = make_uint2(lo, hi);
        }
        ch = ch_nxt;
        xrow = xrow_n;
    }

    #pragma unroll
    for (int b = 0; b < 4; ++b) {
        f32x4 o;
        #pragma unroll
        for (int r = 0; r < 4; ++r) o[r] = hreg[b][r];
        *reinterpret_cast<f32x4*>(out + wid * 64 + b * 16 + lq * 4) = o;
    }
}

extern "C" void kernel_launch(void* const* d_in, const int* in_sizes, int n_in,
                              void* d_out, int out_size, void* d_ws, size_t ws_size,
                              hipStream_t stream) {
    const float* emb = (const float*)d_in[0];
    const float* Wih = (const float*)d_in[1];
    const float* Whh = (const float*)d_in[2];
    const float* bih = (const float*)d_in[3];
    const float* bhh = (const float*)d_in[4];
    const int* chars = (const int*)d_in[5];
    const int* lens  = (const int*)d_in[6];
    float* out = (float*)d_out;

    float*    xtab = (float*)d_ws;              // 25600 f32 = 100 KB
    ushort_t* Wb   = (ushort_t*)(xtab + 25600); // 16384 bf16 = 32 KB
    int*      bh   = (int*)(Wb + 16384);        // 256*16
    int*      bas  = bh + 4096;                 // 256*16
    int*      perm = bas + 4096;                // 65536

    prep_fused<<<VOCAB + 64 + 256, 256, 0, stream>>>(emb, Wih, Whh, bih, bhh, lens, xtab, Wb, bh);
    k_bases<<<1, 256, 0, stream>>>(bh, bas);
    k_scatter<<<256, 256, 0, stream>>>(lens, bas, perm);

    // 1024 blocks x 4 waves = 4096 waves, one 16-word group each
    lstm_main<<<1024, 256, 0, stream>>>(Wb, xtab, chars, lens, perm, out);
}

// Round 6
// 177.802 us; speedup vs baseline: 1.9482x; 1.9482x over previous
//
#include <hip/hip_runtime.h>
#include <hip/hip_bf16.h>

// Char-LSTM via MFMA, round 6.
// Round-5 failure root cause: __launch_bounds__(256,4) capped VGPRs at 128,
// below the ~150-reg working set -> scratch spills (FETCH 380MB, WRITE 115MB,
// VGPR_Count=64). Fix: revert cap to (256,2); the kernel compiles to ~116 VGPR
// which ALREADY allows 4 waves/SIMD in hardware. Keep round-5's real wins:
// 4096-wave grid (1 group/wave), exp2-folded activations, parallel k_bases.
// Class mixing fixed: block's 4 waves take one length-class per quartile.

#define VOCAB 100
#define E     32
#define NW    65536
#define MAXL  16
#define NGRP  4096   // NW/16

typedef __bf16 bf16x8 __attribute__((ext_vector_type(8)));
typedef float  f32x4  __attribute__((ext_vector_type(4)));
typedef unsigned short ushort_t;
typedef unsigned int uint_t;

#define LOG2E    1.4426950408889634f
#define TWOLOG2E 2.8853900817779268f

__device__ __forceinline__ ushort_t f2bf(float x) {
    union { __hip_bfloat16 b; ushort_t u; } cv;
    cv.b = __float2bfloat16(x);
    return cv.u;
}
__device__ __forceinline__ float exp2_hw(float x) { return __builtin_amdgcn_exp2f(x); }
__device__ __forceinline__ float rcp_hw(float x)  { return __builtin_amdgcn_rcpf(x); }

// ---- fused prep: xtab [100][256] f32 (scaled), Wb [256][64] bf16 (scaled), hist ----
__global__ void prep_fused(const float* __restrict__ emb, const float* __restrict__ Wih,
                           const float* __restrict__ Whh, const float* __restrict__ bih,
                           const float* __restrict__ bhh, const int* __restrict__ lengths,
                           float* __restrict__ xtab, ushort_t* __restrict__ Wb,
                           int* __restrict__ bh) {
    int bid = blockIdx.x;
    if (bid < VOCAB) {                         // xtab row: g = q*64+u (torch row order)
        int ch = bid, g = threadIdx.x, q = g >> 6;
        float scl = (q == 2) ? TWOLOG2E : -LOG2E;
        float acc = bih[g] + bhh[g];
        const float* er = emb + ch * E;
        const float* wr = Wih + g * E;
        #pragma unroll
        for (int e = 0; e < E; ++e) acc = fmaf(er[e], wr[e], acc);
        xtab[ch * 256 + g] = acc * scl;
    } else if (bid < VOCAB + 64) {             // Wb = bf16(scaled Whh), [256][64]
        int i = (bid - VOCAB) * 256 + threadIdx.x;
        int q = i >> 12;                       // gate quarter of row (i>>6)
        float scl = (q == 2) ? TWOLOG2E : -LOG2E;
        Wb[i] = f2bf(Whh[i] * scl);
    } else {                                   // per-block length histogram
        int blk = bid - (VOCAB + 64);          // 0..255
        __shared__ int h[16];
        if (threadIdx.x < 16) h[threadIdx.x] = 0;
        __syncthreads();
        atomicAdd(&h[lengths[blk * 256 + threadIdx.x] - 1], 1);
        __syncthreads();
        if (threadIdx.x < 16) bh[blk * 16 + threadIdx.x] = h[threadIdx.x];
    }
}

// parallel exclusive prefix: bases[blk][b] = gb[b] + sum_{blk'<blk} bh[blk'][b]
__global__ void k_bases(const int* __restrict__ bh, int* __restrict__ bases) {
    __shared__ int chunk[16][16], chunkpre[16][16], tot[16], gb[16];
    int t = threadIdx.x, b = t & 15, cs = t >> 4;
    int s = 0;
    #pragma unroll
    for (int i = 0; i < 16; ++i) s += bh[(cs * 16 + i) * 16 + b];
    chunk[cs][b] = s;
    __syncthreads();
    if (t < 16) {                              // thread b scans chunks of bucket b
        int a = 0;
        for (int c2 = 0; c2 < 16; ++c2) { chunkpre[c2][b] = a; a += chunk[c2][b]; }
        tot[b] = a;
    }
    __syncthreads();
    if (t == 0) { int a = 0; for (int i = 0; i < 16; ++i) { gb[i] = a; a += tot[i]; } }
    __syncthreads();
    int base = gb[b] + chunkpre[cs][b];
    for (int i = 0; i < 16; ++i) {
        bases[(cs * 16 + i) * 16 + b] = base;
        base += bh[(cs * 16 + i) * 16 + b];
    }
}

__global__ void k_scatter(const int* __restrict__ lengths, const int* __restrict__ bases,
                          int* __restrict__ perm) {
    __shared__ int h[16];
    if (threadIdx.x < 16) h[threadIdx.x] = 0;
    __syncthreads();
    int w = blockIdx.x * 256 + threadIdx.x;
    int b = lengths[w] - 1;
    int r = atomicAdd(&h[b], 1);
    perm[bases[blockIdx.x * 16 + b] + r] = w;
}

// ---- main ----
__global__ __launch_bounds__(256, 2) void lstm_main(
    const ushort_t* __restrict__ Wb, const float* __restrict__ xtab,
    const int* __restrict__ chars, const int* __restrict__ lengths,
    const int* __restrict__ perm, float* __restrict__ out)
{
    __shared__ __align__(16) char Hlds_all[4][2048];
    char* Hbase = Hlds_all[threadIdx.x >> 6];

    const int lane = threadIdx.x & 63;
    const int w  = lane & 15;                  // word slot (MFMA N-col)
    const int lq = lane >> 4;                  // lane quad
    // class mixing: block's 4 waves get one length-class per quartile
    const int widx = threadIdx.x >> 6;
    const int cls  = (widx << 2) | (blockIdx.x & 3);
    const int grp  = (cls << 8) | (blockIdx.x >> 2);     // 0..4095

    // A-fragments (weights), resident in 64 VGPRs.
    bf16x8 a[16][2];
    #pragma unroll
    for (int m = 0; m < 16; ++m)
        #pragma unroll
        for (int kh = 0; kh < 2; ++kh)
            a[m][kh] = *reinterpret_cast<const bf16x8*>(Wb + ((m * 16 + w) * 64 + kh * 32 + lq * 8));

    // Swizzled per-wave LDS bounce offsets for H (write/read same involution).
    const int sw = (w & 7) << 4;
    const int base_w = w * 128;
    int wr_off[4], rd_off[2];
    #pragma unroll
    for (int b = 0; b < 4; ++b) wr_off[b] = base_w + ((b * 32 + lq * 8) ^ sw);
    #pragma unroll
    for (int kh = 0; kh < 2; ++kh) rd_off[kh] = base_w + ((kh * 64 + lq * 16) ^ sw);

    const int wid = perm[grp * 16 + w];
    const int len = lengths[wid];
    // robust group-max length: max over the 16 word slots
    int ml = len;
    ml = max(ml, __shfl_xor(ml, 1));
    ml = max(ml, __shfl_xor(ml, 2));
    ml = max(ml, __shfl_xor(ml, 4));
    ml = max(ml, __shfl_xor(ml, 8));
    const int maxl = __builtin_amdgcn_readfirstlane(ml);
    const int* chp = chars + wid * MAXL;

    float hreg[4][4], creg[4][4];
    #pragma unroll
    for (int b = 0; b < 4; ++b)
        #pragma unroll
        for (int r = 0; r < 4; ++r) { hreg[b][r] = 0.f; creg[b][r] = 0.f; }

    int ch = chp[0];
    const float* xrow = xtab + ch * 256;
    f32x4 xtb[2][4];
    #pragma unroll
    for (int q = 0; q < 4; ++q)
        xtb[0][q] = *reinterpret_cast<const f32x4*>(xrow + (q * 4 + 0) * 16 + lq * 4);

    #pragma unroll 1
    for (int t = 0; t < maxl; ++t) {
        const int tn = (t + 1 < maxl) ? t + 1 : t;
        const int ch_nxt = chp[tn];
        const float* xrow_n = xtab + ch_nxt * 256;

        bf16x8 B0, B1;
        if (t > 0) {
            asm volatile("s_waitcnt lgkmcnt(0)" ::: "memory");   // prev-step H writes
            B0 = *reinterpret_cast<const bf16x8*>(Hbase + rd_off[0]);
            B1 = *reinterpret_cast<const bf16x8*>(Hbase + rd_off[1]);
        }
        const bool act = (t < len);

        #pragma unroll
        for (int b = 0; b < 4; ++b) {
            if (b < 3) {
                #pragma unroll
                for (int q = 0; q < 4; ++q)
                    xtb[(b + 1) & 1][q] = *reinterpret_cast<const f32x4*>(xrow + (q * 4 + b + 1) * 16 + lq * 4);
            } else {
                #pragma unroll
                for (int q = 0; q < 4; ++q)
                    xtb[0][q] = *reinterpret_cast<const f32x4*>(xrow_n + q * 64 + lq * 4);
            }
            f32x4 d[4];
            #pragma unroll
            for (int q = 0; q < 4; ++q) d[q] = xtb[b & 1][q];
            if (t > 0) {
                #pragma unroll
                for (int q = 0; q < 4; ++q) {
                    d[q] = __builtin_amdgcn_mfma_f32_16x16x32_bf16(a[q * 4 + b][0], B0, d[q], 0, 0, 0);
                    d[q] = __builtin_amdgcn_mfma_f32_16x16x32_bf16(a[q * 4 + b][1], B1, d[q], 0, 0, 0);
                }
            }
            // activations in exp2-folded space: d0=i', d1=f', d2=g', d3=o'
            #pragma unroll
            for (int r = 0; r < 4; ++r) {
                float ig = rcp_hw(1.f + exp2_hw(d[0][r]));
                float fg = rcp_hw(1.f + exp2_hw(d[1][r]));
                float gg = fmaf(-2.f, rcp_hw(1.f + exp2_hw(d[2][r])), 1.f);
                float og = rcp_hw(1.f + exp2_hw(d[3][r]));
                float cn = fmaf(fg, creg[b][r], ig * gg);
                float tc = fmaf(-2.f, rcp_hw(1.f + exp2_hw(cn * TWOLOG2E)), 1.f);
                float hn = og * tc;
                creg[b][r] = act ? cn : creg[b][r];
                hreg[b][r] = act ? hn : hreg[b][r];
            }
            uint_t lo = (uint_t)f2bf(hreg[b][0]) | ((uint_t)f2bf(hreg[b][1]) << 16);
            uint_t hi = (uint_t)f2bf(hreg[b][2]) | ((uint_t)f2bf(hreg[b][3]) << 16);
            *reinterpret_cast<uint2*>(Hbase + wr_off[b]) = make_uint2(lo, hi);
        }
        ch = ch_nxt;
        xrow = xrow_n;
    }

    #pragma unroll
    for (int b = 0; b < 4; ++b) {
        f32x4 o;
        #pragma unroll
        for (int r = 0; r < 4; ++r) o[r] = hreg[b][r];
        *reinterpret_cast<f32x4*>(out + wid * 64 + b * 16 + lq * 4) = o;
    }
}

extern "C" void kernel_launch(void* const* d_in, const int* in_sizes, int n_in,
                              void* d_out, int out_size, void* d_ws, size_t ws_size,
                              hipStream_t stream) {
    const float* emb = (const float*)d_in[0];
    const float* Wih = (const float*)d_in[1];
    const float* Whh = (const float*)d_in[2];
    const float* bih = (const float*)d_in[3];
    const float* bhh = (const float*)d_in[4];
    const int* chars = (const int*)d_in[5];
    const int* lens  = (const int*)d_in[6];
    float* out = (float*)d_out;

    float*    xtab = (float*)d_ws;              // 25600 f32 = 100 KB
    ushort_t* Wb   = (ushort_t*)(xtab + 25600); // 16384 bf16 = 32 KB
    int*      bh   = (int*)(Wb + 16384);        // 256*16
    int*      bas  = bh + 4096;                 // 256*16
    int*      perm = bas + 4096;                // 65536

    prep_fused<<<VOCAB + 64 + 256, 256, 0, stream>>>(emb, Wih, Whh, bih, bhh, lens, xtab, Wb, bh);
    k_bases<<<1, 256, 0, stream>>>(bh, bas);
    k_scatter<<<256, 256, 0, stream>>>(lens, bas, perm);

    // 1024 blocks x 4 waves = 4096 waves, one 16-word group each
    lstm_main<<<1024, 256, 0, stream>>>(Wb, xtab, chars, lens, perm, out);
}

// Round 7
// 155.536 us; speedup vs baseline: 2.2271x; 1.1432x over previous
//
#include <hip/hip_runtime.h>
#include <hip/hip_bf16.h>

// Char-LSTM via MFMA, round 7.
// Round-6 diagnosis: (a) class-mixing correlated length-class with SIMD slot
// (widx) -> SIMD 3 got all long groups, VALUBusy 30%, eff. occupancy ~1.1
// waves/SIMD; (b) issue is dominated by quarter-rate trans ops (10/cell).
// Fixes: complementary group pairing (wave g does groups g and 4095-g -> every
// wave exactly ~17 steps, SIMD-balance independent of dispatch); shared-rcp
// activation forms (8 trans/cell); sort folded into 2 prep kernels.

#define VOCAB 100
#define E     32
#define NW    65536
#define MAXL  16
#define NGRP  4096   // NW/16

typedef __bf16 bf16x8 __attribute__((ext_vector_type(8)));
typedef float  f32x4  __attribute__((ext_vector_type(4)));
typedef unsigned short ushort_t;
typedef unsigned int uint_t;

#define LOG2E    1.4426950408889634f
#define TWOLOG2E 2.8853900817779268f

__device__ __forceinline__ ushort_t f2bf(float x) {
    union { __hip_bfloat16 b; ushort_t u; } cv;
    cv.b = __float2bfloat16(x);
    return cv.u;
}
__device__ __forceinline__ float exp2_hw(float x) { return __builtin_amdgcn_exp2f(x); }
__device__ __forceinline__ float rcp_hw(float x)  { return __builtin_amdgcn_rcpf(x); }

// ---- K1: xtab [100][256] f32 (scaled), Wb [256][64] bf16 (scaled), hist bh[256][16] ----
__global__ void prep_all(const float* __restrict__ emb, const float* __restrict__ Wih,
                         const float* __restrict__ Whh, const float* __restrict__ bih,
                         const float* __restrict__ bhh, const int* __restrict__ lengths,
                         float* __restrict__ xtab, ushort_t* __restrict__ Wb,
                         int* __restrict__ bh) {
    int bid = blockIdx.x;
    if (bid < VOCAB) {                         // xtab row: g = q*64+u (torch row order)
        int ch = bid, g = threadIdx.x, q = g >> 6;
        float scl = (q == 2) ? TWOLOG2E : -LOG2E;
        float acc = bih[g] + bhh[g];
        const float* er = emb + ch * E;
        const float* wr = Wih + g * E;
        #pragma unroll
        for (int e = 0; e < E; ++e) acc = fmaf(er[e], wr[e], acc);
        xtab[ch * 256 + g] = acc * scl;
    } else if (bid < VOCAB + 64) {             // Wb = bf16(scaled Whh), [256][64]
        int i = (bid - VOCAB) * 256 + threadIdx.x;
        int q = i >> 12;                       // gate quarter of row (i>>6)
        float scl = (q == 2) ? TWOLOG2E : -LOG2E;
        Wb[i] = f2bf(Whh[i] * scl);
    } else {                                   // per-block length histogram
        int blk = bid - (VOCAB + 64);          // 0..255
        __shared__ int h[16];
        if (threadIdx.x < 16) h[threadIdx.x] = 0;
        __syncthreads();
        atomicAdd(&h[lengths[blk * 256 + threadIdx.x] - 1], 1);
        __syncthreads();
        if (threadIdx.x < 16) bh[blk * 16 + threadIdx.x] = h[threadIdx.x];
    }
}

// ---- K2: sort (bases recomputed per block from bh, then scatter) ----
__global__ void k_sort(const int* __restrict__ lengths, const int* __restrict__ bh,
                       int* __restrict__ perm) {
    __shared__ int lbh[4096];                  // bh copy, 16 KB
    __shared__ int pre[16], tot[16], gb[16], mybase[16], hh[16];
    const int t = threadIdx.x, B = blockIdx.x;
    for (int i = t; i < 4096; i += 256) lbh[i] = bh[i];
    if (t < 16) hh[t] = 0;
    __syncthreads();
    if (t < 16) {
        int s = 0;
        for (int B2 = 0; B2 < B; ++B2) s += lbh[B2 * 16 + t];
        int tt = s;
        for (int B2 = B; B2 < 256; ++B2) tt += lbh[B2 * 16 + t];
        pre[t] = s; tot[t] = tt;
    }
    __syncthreads();
    if (t == 0) { int a = 0; for (int i = 0; i < 16; ++i) { gb[i] = a; a += tot[i]; } }
    __syncthreads();
    if (t < 16) mybase[t] = gb[t] + pre[t];
    __syncthreads();
    int w = B * 256 + t;
    int b = lengths[w] - 1;
    int r = atomicAdd(&hh[b], 1);
    perm[mybase[b] + r] = w;
}

// ---- K3: main ----
__global__ __launch_bounds__(256, 2) void lstm_main(
    const ushort_t* __restrict__ Wb, const float* __restrict__ xtab,
    const int* __restrict__ chars, const int* __restrict__ lengths,
    const int* __restrict__ perm, float* __restrict__ out)
{
    __shared__ __align__(16) char Hlds_all[4][2048];
    char* Hbase = Hlds_all[threadIdx.x >> 6];

    const int lane = threadIdx.x & 63;
    const int w  = lane & 15;                  // word slot (MFMA N-col)
    const int lq = lane >> 4;                  // lane quad
    const int wave = (blockIdx.x << 2) + (threadIdx.x >> 6);   // 0..2047

    // A-fragments (weights), resident in 64 VGPRs.
    bf16x8 a[16][2];
    #pragma unroll
    for (int m = 0; m < 16; ++m)
        #pragma unroll
        for (int kh = 0; kh < 2; ++kh)
            a[m][kh] = *reinterpret_cast<const bf16x8*>(Wb + ((m * 16 + w) * 64 + kh * 32 + lq * 8));

    // Swizzled per-wave LDS bounce offsets for H (write/read same involution).
    const int sw = (w & 7) << 4;
    const int base_w = w * 128;
    int wr_off[4], rd_off[2];
    #pragma unroll
    for (int b = 0; b < 4; ++b) wr_off[b] = base_w + ((b * 32 + lq * 8) ^ sw);
    #pragma unroll
    for (int kh = 0; kh < 2; ++kh) rd_off[kh] = base_w + ((kh * 64 + lq * 16) ^ sw);

    #pragma unroll 1
    for (int gi = 0; gi < 2; ++gi) {
        const int grp = gi ? (NGRP - 1 - wave) : wave;   // complementary pair: ~17 steps total
        const int wid = perm[grp * 16 + w];
        const int len = lengths[wid];
        int ml = len;                                    // group-max length over 16 slots
        ml = max(ml, __shfl_xor(ml, 1));
        ml = max(ml, __shfl_xor(ml, 2));
        ml = max(ml, __shfl_xor(ml, 4));
        ml = max(ml, __shfl_xor(ml, 8));
        const int maxl = __builtin_amdgcn_readfirstlane(ml);
        const int* chp = chars + wid * MAXL;

        float hreg[4][4], creg[4][4];
        #pragma unroll
        for (int b = 0; b < 4; ++b)
            #pragma unroll
            for (int r = 0; r < 4; ++r) { hreg[b][r] = 0.f; creg[b][r] = 0.f; }

        int ch = chp[0];
        const float* xrow = xtab + ch * 256;
        f32x4 xtb[2][4];
        #pragma unroll
        for (int q = 0; q < 4; ++q)
            xtb[0][q] = *reinterpret_cast<const f32x4*>(xrow + (q * 4 + 0) * 16 + lq * 4);

        #pragma unroll 1
        for (int t = 0; t < maxl; ++t) {
            const int tn = (t + 1 < maxl) ? t + 1 : t;
            const int ch_nxt = chp[tn];
            const float* xrow_n = xtab + ch_nxt * 256;

            bf16x8 B0, B1;
            if (t > 0) {
                asm volatile("s_waitcnt lgkmcnt(0)" ::: "memory");   // prev-step H writes
                B0 = *reinterpret_cast<const bf16x8*>(Hbase + rd_off[0]);
                B1 = *reinterpret_cast<const bf16x8*>(Hbase + rd_off[1]);
            }
            const bool act = (t < len);

            #pragma unroll
            for (int b = 0; b < 4; ++b) {
                if (b < 3) {
                    #pragma unroll
                    for (int q = 0; q < 4; ++q)
                        xtb[(b + 1) & 1][q] = *reinterpret_cast<const f32x4*>(xrow + (q * 4 + b + 1) * 16 + lq * 4);
                } else {
                    #pragma unroll
                    for (int q = 0; q < 4; ++q)
                        xtb[0][q] = *reinterpret_cast<const f32x4*>(xrow_n + q * 64 + lq * 4);
                }
                f32x4 d[4];
                #pragma unroll
                for (int q = 0; q < 4; ++q) d[q] = xtb[b & 1][q];
                if (t > 0) {
                    #pragma unroll
                    for (int q = 0; q < 4; ++q) {
                        d[q] = __builtin_amdgcn_mfma_f32_16x16x32_bf16(a[q * 4 + b][0], B0, d[q], 0, 0, 0);
                        d[q] = __builtin_amdgcn_mfma_f32_16x16x32_bf16(a[q * 4 + b][1], B1, d[q], 0, 0, 0);
                    }
                }
                // shared-rcp activations (8 trans/cell):
                // d0=i', d1=f', d2=g', d3=o' (i,f,o scaled -log2e; g scaled 2log2e)
                // ig*gg = (ug-1)/((1+ui)(1+ug));  h = og*tanh(c) = (uc-1)/((1+uo)(1+uc))
                #pragma unroll
                for (int r = 0; r < 4; ++r) {
                    float ui = exp2_hw(d[0][r]);
                    float uf = exp2_hw(d[1][r]);
                    float ug = exp2_hw(d[2][r]);
                    float uo = exp2_hw(d[3][r]);
                    float ti = 1.f + ui, tg = 1.f + ug;
                    float igg = (ug - 1.f) * rcp_hw(ti * tg);
                    float fg  = rcp_hw(1.f + uf);
                    float cn  = fmaf(fg, creg[b][r], igg);
                    float uc  = exp2_hw(cn * TWOLOG2E);
                    float to  = 1.f + uo, tc = 1.f + uc;
                    float hn  = (uc - 1.f) * rcp_hw(to * tc);
                    creg[b][r] = act ? cn : creg[b][r];
                    hreg[b][r] = act ? hn : hreg[b][r];
                }
                uint_t lo = (uint_t)f2bf(hreg[b][0]) | ((uint_t)f2bf(hreg[b][1]) << 16);
                uint_t hi = (uint_t)f2bf(hreg[b][2]) | ((uint_t)f2bf(hreg[b][3]) << 16);
                *reinterpret_cast<uint2*>(Hbase + wr_off[b]) = make_uint2(lo, hi);
            }
            ch = ch_nxt;
            xrow = xrow_n;
        }

        #pragma unroll
        for (int b = 0; b < 4; ++b) {
            f32x4 o;
            #pragma unroll
            for (int r = 0; r < 4; ++r) o[r] = hreg[b][r];
            *reinterpret_cast<f32x4*>(out + wid * 64 + b * 16 + lq * 4) = o;
        }
    }
}

extern "C" void kernel_launch(void* const* d_in, const int* in_sizes, int n_in,
                              void* d_out, int out_size, void* d_ws, size_t ws_size,
                              hipStream_t stream) {
    const float* emb = (const float*)d_in[0];
    const float* Wih = (const float*)d_in[1];
    const float* Whh = (const float*)d_in[2];
    const float* bih = (const float*)d_in[3];
    const float* bhh = (const float*)d_in[4];
    const int* chars = (const int*)d_in[5];
    const int* lens  = (const int*)d_in[6];
    float* out = (float*)d_out;

    float*    xtab = (float*)d_ws;              // 25600 f32 = 100 KB
    ushort_t* Wb   = (ushort_t*)(xtab + 25600); // 16384 bf16 = 32 KB
    int*      bh   = (int*)(Wb + 16384);        // 256*16
    int*      perm = bh + 4096;                 // 65536

    prep_all<<<VOCAB + 64 + 256, 256, 0, stream>>>(emb, Wih, Whh, bih, bhh, lens, xtab, Wb, bh);
    k_sort<<<256, 256, 0, stream>>>(lens, bh, perm);

    // 512 blocks x 4 waves = 2048 waves; wave g does groups g and 4095-g (~17 steps)
    lstm_main<<<512, 256, 0, stream>>>(Wb, xtab, chars, lens, perm, out);
}